// Round 15
// baseline (334.771 us; speedup 1.0000x reference)
//
#include <hip/hip_runtime.h>
#include <math.h>

// ---------------------------------------------------------------------------
// MPNNPropPred: N=20000 nodes, E=50000 edges, B=128 graphs, H=64,
// FEAT=28, N_TYPES=100, EDGE_DIM=5, MP_ITER=3, S2S_IT=4. All f32.
// R19: R18 (205.2 us, best) minus the k_pre dispatch — the DAG minimum
//   without grid sync is 5 dispatches:
//   - place blocks self-compute their type-prefix from raw etype (all 4
//     waves, ballot + shared-atomic count of the 200-KB L2-resident array;
//     196 uniform iterations; replaces bc exactly)
//   - k_s2s binary-searches batch[] for its graph range (lower_bound x2,
//     2 threads x 15 L2 probes; replaces gstart exactly, empty-graph-safe)
//   k_mp (R12-proven) and all other sub-phases byte-identical to R18.
//   Dispatches: k_main, 3x k_mp, k_s2s = 5.
// ---------------------------------------------------------------------------

#define NN 20000
#define NE 50000
#define NB 128
#define HD 64
#define NFEAT 28
#define NTYPES 100
#define EDIM 5
#define MPIT 3
#define S2SIT 4
#define NBLK_E ((NE + 255) / 256)  // 196 fixed-range edge blocks
#define EPAD (NBLK_E * 256)        // 50176 = padded edge count (uniform loop)
#define SMAX 224                   // nodes cached in LDS (max graph ~195)
#define HP (HD + 1)                // padded LDS row stride
#define EPW 7                      // edges per wave in k_mp (8192 waves)

__device__ __forceinline__ float sigm(float x) {
  return 1.0f / (1.0f + expf(-x));
}

__device__ __forceinline__ float rdlane(float v, int l) {
  return __uint_as_float(__builtin_amdgcn_readlane(__float_as_uint(v), l));
}

// --- k_main: edgemats | place (self-prefix) | LSTM transposes | embed |
//     zero hB. All sub-jobs independent; grid 512x256. ---
__global__ __launch_bounds__(256) void k_main(
    const float* __restrict__ feat, const int* __restrict__ ntype,
    const int* __restrict__ etype, const int* __restrict__ ei,
    const float* __restrict__ W_emb, const float* __restrict__ b_emb,
    const float* __restrict__ W_e1, const float* __restrict__ b_e1,
    const float* __restrict__ W_e2, const float* __restrict__ b_e2,
    const float* __restrict__ W_ih, const float* __restrict__ W_hh,
    float* __restrict__ Wty, float* __restrict__ hA, float* __restrict__ hB,
    float* __restrict__ W_ihT, float* __restrict__ W_hhT,
    int2* __restrict__ sd) {
  __shared__ float sv[EDIM][HD];       // relu(W_e1+b_e1) per type
  __shared__ float red[4][EDIM][HD];   // j-group partial sums
  __shared__ int s_base[EDIM];
  __shared__ int s_part[EDIM], s_tot[EDIM];
  __shared__ int wc[4][EDIM];
  const int tid = threadIdx.x;
  const int lane = tid & 63;
  const int wv = tid >> 6;
  const int blk = blockIdx.x;
  const int nblk = gridDim.x;
  const int nthr = nblk << 8;
  const int gtid = (blk << 8) + tid;
  const int gw = (blk << 2) + wv;
  const int nwave = nblk << 2;

  // 1) edge-type weight matrices, latency-robust (blocks 0..63):
  //    thread (jg,l): 16 coalesced W_e2 loads, 5 type-accs, LDS reduce.
  if (blk < 64) {
    int mbase = blk * 64;
    for (int idx = tid; idx < EDIM * HD; idx += 256) {
      int t = idx >> 6, j = idx & 63;
      float x = W_e1[t * HD + j] + b_e1[j];
      sv[t][j] = x > 0.f ? x : 0.f;
    }
    __syncthreads();
    int l = tid & 63, jg = tid >> 6;
    float acc[EDIM] = {0.f, 0.f, 0.f, 0.f, 0.f};
    #pragma unroll
    for (int jj = 0; jj < 16; ++jj) {
      int j = jg * 16 + jj;
      float w2 = W_e2[j * 4096 + mbase + l];   // coalesced, independent
      #pragma unroll
      for (int t = 0; t < EDIM; ++t) acc[t] = fmaf(sv[t][j], w2, acc[t]);
    }
    #pragma unroll
    for (int t = 0; t < EDIM; ++t) red[jg][t][l] = acc[t];
    __syncthreads();
    for (int idx = tid; idx < EDIM * HD; idx += 256) {
      int t = idx >> 6, m = idx & 63;
      float s = red[0][t][m] + red[1][t][m] + red[2][t][m] + red[3][t][m];
      Wty[t * 4096 + mbase + m] = s + b_e2[mbase + m];
    }
  }

  // 2) place edges grouped by type (blocks 64..259). Each block computes
  //    its own scan base by ballot-counting the raw etype array (200 KB,
  //    L2-resident; uniform 196-iteration loop so ballots are well-defined).
  if (blk >= 64 && blk < 64 + NBLK_E) {
    int pblk = blk - 64;
    int plim = pblk << 8;
    if (tid < EDIM) { s_part[tid] = 0; s_tot[tid] = 0; }
    __syncthreads();
    for (int i = tid; i < EPAD; i += 256) {     // EPAD = 196*256, uniform
      int ty2 = (i < NE) ? etype[i] : -1;
      #pragma unroll
      for (int t = 0; t < EDIM; ++t) {
        unsigned long long m  = __ballot(ty2 == t);
        unsigned long long mp = __ballot(ty2 == t && i < plim);
        if (lane == 0) {
          if (m)  atomicAdd(&s_tot[t],  __popcll(m));
          if (mp) atomicAdd(&s_part[t], __popcll(mp));
        }
      }
    }
    __syncthreads();
    if (tid == 0) {
      int run = 0;
      #pragma unroll
      for (int t = 0; t < EDIM; ++t) {
        s_base[t] = run + s_part[t];
        run += s_tot[t];
      }
    }
    __syncthreads();

    // ballot ranks within the block's fixed 256-edge range (R7-proven)
    int e = plim + tid;
    int ty = (e < NE) ? etype[e] : -1;
    int svv = 0, dv = 0;
    if (e < NE) { svv = ei[e]; dv = ei[NE + e]; }
    int rank = 0;
    #pragma unroll
    for (int t = 0; t < EDIM; ++t) {
      unsigned long long m = __ballot(ty == t);
      if (lane == 0) wc[wv][t] = __popcll(m);
      if (ty == t) rank = __popcll(m & ((1ull << lane) - 1ull));
    }
    __syncthreads();
    if (ty >= 0) {
      int base = s_base[ty];
      for (int w = 0; w < wv; ++w) base += wc[w][ty];
      sd[base + rank] = make_int2(svv | (ty << 16), dv);
    }
  }

  // 3) LSTM weight transposes (coalesced writes)
  for (int o = gtid; o < 2 * HD * 4 * HD; o += nthr)       // W_ihT [128][256]
    W_ihT[o] = W_ih[(o & 255) * 128 + (o >> 8)];
  for (int o = gtid; o < HD * 4 * HD; o += nthr)           // W_hhT [64][256]
    W_hhT[o] = W_hh[(o & 255) * 64 + (o >> 8)];

  // 4) node embedding: wave per node, feature weights hoisted to VGPRs
  {
    float wf[NFEAT];
    #pragma unroll
    for (int f = 0; f < NFEAT; ++f) wf[f] = W_emb[(NTYPES + f) * HD + lane];
    float bb = b_emb[lane];
    for (int n = gw; n < NN; n += nwave) {
      int nu = __builtin_amdgcn_readfirstlane(n);
      int t = __builtin_amdgcn_readfirstlane(ntype[nu]);
      const float* row = feat + nu * NFEAT;        // wave-uniform -> s_load
      float acc = bb + W_emb[t * HD + lane];
      #pragma unroll
      for (int f = 0; f < NFEAT; ++f) acc = fmaf(row[f], wf[f], acc);
      hA[nu * HD + lane] = acc;
    }
  }

  // 5) zero hB (target of first MP iteration)
  {
    float4 z = make_float4(0.f, 0.f, 0.f, 0.f);
    for (int i = gtid; i < NN * HD / 4; i += nthr)
      reinterpret_cast<float4*>(hB)[i] = z;
  }
}

// --- one MP iteration (R12-proven, verbatim): blocks 0..511 root
//     (atomicAdd into zeroed tgt) + zero next target; blocks 512..2559
//     edge messages with staged vector loads + readlane broadcast.
__global__ __launch_bounds__(256) void k_mp(
    const int2* __restrict__ sd,
    const float* __restrict__ Wty, const float* __restrict__ hsrc,
    float* __restrict__ htgt, float* __restrict__ hzero,
    const float* __restrict__ root, const float* __restrict__ bias) {
  const int lane = threadIdx.x & 63;
  const int wv = threadIdx.x >> 6;
  const int blk = blockIdx.x;

  if (blk < 512) {
    // NNConv root matvec + bias, atomicAdd into zero-initialized target
    float w[HD];
    #pragma unroll
    for (int k = 0; k < HD; ++k) w[k] = root[k * HD + lane];
    float bb = bias[lane];
    int rw = (blk << 2) + wv;                    // 0..2047
    for (int n = rw; n < NN; n += 2048) {
      int nu = __builtin_amdgcn_readfirstlane(n);
      const float* row = hsrc + nu * HD;         // wave-uniform -> s_load
      float a0 = bb, a1 = 0.f, a2 = 0.f, a3 = 0.f;
      #pragma unroll
      for (int k = 0; k < HD; k += 4) {
        a0 = fmaf(row[k + 0], w[k + 0], a0);
        a1 = fmaf(row[k + 1], w[k + 1], a1);
        a2 = fmaf(row[k + 2], w[k + 2], a2);
        a3 = fmaf(row[k + 3], w[k + 3], a3);
      }
      atomicAdd(&htgt[nu * HD + lane], (a0 + a1) + (a2 + a3));
    }
    // zero next iteration's target (overlaps with this phase's traffic)
    if (hzero) {
      float4 z = make_float4(0.f, 0.f, 0.f, 0.f);
      for (int i = (blk << 8) + threadIdx.x; i < NN * HD / 4; i += 512 * 256)
        reinterpret_cast<float4*>(hzero)[i] = z;
    }
  } else {
    // edge messages: wave handles EPW consecutive type-sorted edges
    int wid = ((blk - 512) << 2) + wv;           // 0..8191
    int beg = wid * EPW;
    if (beg >= NE) return;
    int len = NE - beg; if (len > EPW) len = EPW;

    // one per-lane load fetches the wave's edge records (lanes 0..len-1)
    int2 ed = sd[beg + (lane < len ? lane : len - 1)];

    // stage all h rows as independent coalesced vector loads (in flight)
    float hv[EPW];
    #pragma unroll
    for (int j = 0; j < EPW; ++j) {
      int sx = __builtin_amdgcn_readlane(ed.x, j < EPW ? j : 0);
      // j >= len reads lane len-1's record: valid address, result unused
      hv[j] = hsrc[(sx & 0xFFFF) * HD + lane];
    }

    int curt = -1;
    float w[HD];
    #pragma unroll
    for (int j = 0; j < EPW; ++j) {
      if (j >= len) break;
      int ex = __builtin_amdgcn_readlane(ed.x, j);
      int dj = __builtin_amdgcn_readlane(ed.y, j);
      int ty = ex >> 16;
      if (ty != curt) {                          // rare: type-segment switch
        curt = ty;
        #pragma unroll
        for (int k = 0; k < HD; ++k) w[k] = Wty[ty * 4096 + k * HD + lane];
      }
      float a0 = 0.f, a1 = 0.f, a2 = 0.f, a3 = 0.f;
      #pragma unroll
      for (int k = 0; k < HD; k += 4) {
        a0 = fmaf(rdlane(hv[j], k + 0), w[k + 0], a0);
        a1 = fmaf(rdlane(hv[j], k + 1), w[k + 1], a1);
        a2 = fmaf(rdlane(hv[j], k + 2), w[k + 2], a2);
        a3 = fmaf(rdlane(hv[j], k + 3), w[k + 3], a3);
      }
      atomicAdd(&htgt[dj * HD + lane], (a0 + a1) + (a2 + a3));
    }
  }
}

// --- Set2Set + output MLP, one block per graph (proven R4 body).
//     Graph range via binary search in sorted batch[] (replaces gstart;
//     lower_bound(b)/lower_bound(b+1) == old gstart[b]/gstart[b+1]).
__global__ __launch_bounds__(256) void k_s2s(
    const float* __restrict__ h, const int* __restrict__ batch,
    const float* __restrict__ W_ihT, const float* __restrict__ W_hhT,
    const float* __restrict__ b_ih, const float* __restrict__ b_hh,
    const float* __restrict__ W_o1, const float* __restrict__ b_o1,
    const float* __restrict__ W_o2, const float* __restrict__ b_o2,
    float* __restrict__ out) {
  __shared__ float hs[SMAX * HP];     // 58240 B, padded rows
  __shared__ float ebuf[SMAX];
  __shared__ float qstar[2 * HD];
  __shared__ float hxs[HD], cxs[HD], gates[4 * HD];
  __shared__ float redM[4], redS[4], redR[4][HD];
  __shared__ float hid[HD];
  __shared__ int s_st, s_en;
  int b = blockIdx.x;
  int tid = threadIdx.x;
  int lane = tid & 63, wv = tid >> 6;

  // binary search: st = lower_bound(batch, b), en = lower_bound(batch, b+1)
  if (tid < 2) {
    int key = b + tid;
    int lo = 0, hi = NN;
    while (lo < hi) {
      int mid = (lo + hi) >> 1;
      if (batch[mid] < key) lo = mid + 1; else hi = mid;
    }
    if (tid == 0) s_st = lo; else s_en = lo;
  }
  __syncthreads();
  int st = s_st, en = s_en;
  int cnt = en - st;
  int cached = cnt < SMAX ? cnt : SMAX;

  // stage node block into padded LDS (coalesced float4 global reads)
  int total = cached * HD;
  for (int base = tid * 4; base < total; base += 1024) {
    float4 v = *reinterpret_cast<const float4*>(h + st * HD + base);
    int n = base >> 6, k = base & 63;
    float* row = hs + n * HP + k;
    row[0] = v.x; row[1] = v.y; row[2] = v.z; row[3] = v.w;
  }
  if (tid < 2 * HD) qstar[tid] = 0.f;
  if (tid < HD) { hxs[tid] = 0.f; cxs[tid] = 0.f; }
  __syncthreads();

  for (int it = 0; it < S2SIT; ++it) {
    // LSTM gates via transposed weights (coalesced): tid = gate index
    float acc0 = b_ih[tid] + b_hh[tid], acc1 = 0.f;
    #pragma unroll 8
    for (int j = 0; j < 2 * HD; j += 2) {
      acc0 = fmaf(qstar[j],     W_ihT[j * 256 + tid],       acc0);
      acc1 = fmaf(qstar[j + 1], W_ihT[(j + 1) * 256 + tid], acc1);
    }
    #pragma unroll 8
    for (int j = 0; j < HD; j += 2) {
      acc0 = fmaf(hxs[j],     W_hhT[j * 256 + tid],       acc0);
      acc1 = fmaf(hxs[j + 1], W_hhT[(j + 1) * 256 + tid], acc1);
    }
    gates[tid] = acc0 + acc1;
    __syncthreads();
    if (tid < HD) {
      float ig = sigm(gates[tid]);
      float fg = sigm(gates[HD + tid]);
      float gg = tanhf(gates[2 * HD + tid]);
      float og = sigm(gates[3 * HD + tid]);
      float c = fmaf(fg, cxs[tid], ig * gg);
      cxs[tid] = c;
      hxs[tid] = og * tanhf(c);
    }
    __syncthreads();

    // pass 1: per-thread dot (thread = node), padded LDS rows
    float e = -1e30f;
    if (tid < cached) {
      const float* row = hs + tid * HP;
      float d0 = 0.f, d1 = 0.f;
      #pragma unroll 8
      for (int k = 0; k < HD; k += 2) {
        d0 = fmaf(row[k],     hxs[k],     d0);
        d1 = fmaf(row[k + 1], hxs[k + 1], d1);
      }
      e = d0 + d1;
      ebuf[tid] = e;
    }
    float m = e;
    #pragma unroll
    for (int off = 32; off; off >>= 1) m = fmaxf(m, __shfl_xor(m, off, 64));
    float qreg = hxs[lane];
    for (int n = cached + wv; n < cnt; n += 4) {   // overflow tail
      float ev = h[(st + n) * HD + lane] * qreg;
      #pragma unroll
      for (int off = 32; off; off >>= 1) ev += __shfl_xor(ev, off, 64);
      m = fmaxf(m, ev);
    }
    if (lane == 0) redM[wv] = m;
    __syncthreads();
    float M = fmaxf(fmaxf(redM[0], redM[1]), fmaxf(redM[2], redM[3]));

    // pass 2a: a = exp(e-M), per-wave partial sum
    float sp = 0.f;
    if (tid < cached) {
      float a = expf(ebuf[tid] - M);
      ebuf[tid] = a;
      sp = a;
    }
    #pragma unroll
    for (int off = 32; off; off >>= 1) sp += __shfl_xor(sp, off, 64);
    __syncthreads();   // ebuf(a) visible to all waves

    // pass 2b: r = sum_n a[n] * h_n  (lane = feature)
    float r = 0.f;
    for (int n = wv; n < cached; n += 4)
      r = fmaf(ebuf[n], hs[n * HP + lane], r);
    float s_tail = 0.f;
    for (int n = cached + wv; n < cnt; n += 4) {   // overflow tail
      float v = h[(st + n) * HD + lane];
      float ev = v * qreg;
      #pragma unroll
      for (int off = 32; off; off >>= 1) ev += __shfl_xor(ev, off, 64);
      float a = expf(ev - M);
      s_tail += a;
      r = fmaf(a, v, r);
    }
    if (lane == 0) redS[wv] = sp + s_tail;
    redR[wv][lane] = r;
    __syncthreads();
    if (tid < HD) {
      float S = redS[0] + redS[1] + redS[2] + redS[3];
      float R = redR[0][tid] + redR[1][tid] + redR[2][tid] + redR[3][tid];
      if (S == 0.f) S = 1.f;            // empty-graph guard (matches ref)
      qstar[tid] = hxs[tid];
      qstar[HD + tid] = R / S;
    }
    __syncthreads();
  }

  // output MLP: relu(qstar @ W_o1 + b_o1) @ W_o2 + b_o2
  if (tid < HD) {
    float acc = b_o1[tid];
    #pragma unroll 8
    for (int i = 0; i < 2 * HD; ++i)
      acc = fmaf(qstar[i], W_o1[i * HD + tid], acc);
    hid[tid] = acc > 0.f ? acc : 0.f;
  }
  __syncthreads();
  if (tid < HD) {
    float p = hid[tid] * W_o2[tid];
    #pragma unroll
    for (int off = 32; off; off >>= 1) p += __shfl_xor(p, off, 64);
    if (tid == 0) out[b] = p + b_o2[0];
  }
}

extern "C" void kernel_launch(void* const* d_in, const int* in_sizes, int n_in,
                              void* d_out, int out_size, void* d_ws, size_t ws_size,
                              hipStream_t stream) {
  const float* node_feat = (const float*)d_in[0];
  const int*   node_type = (const int*)d_in[1];
  const int*   edge_index= (const int*)d_in[2];
  const int*   edge_type = (const int*)d_in[3];
  const int*   batch     = (const int*)d_in[4];
  const float* W_emb     = (const float*)d_in[5];
  const float* b_emb     = (const float*)d_in[6];
  const float* W_e1      = (const float*)d_in[7];
  const float* b_e1      = (const float*)d_in[8];
  const float* W_e2      = (const float*)d_in[9];
  const float* b_e2      = (const float*)d_in[10];
  const float* roots     = (const float*)d_in[11];
  const float* conv_bias = (const float*)d_in[12];
  const float* W_ih      = (const float*)d_in[13];
  const float* W_hh      = (const float*)d_in[14];
  const float* b_ih      = (const float*)d_in[15];
  const float* b_hh      = (const float*)d_in[16];
  const float* W_o1      = (const float*)d_in[17];
  const float* b_o1      = (const float*)d_in[18];
  const float* W_o2      = (const float*)d_in[19];
  const float* b_o2      = (const float*)d_in[20];
  float* out = (float*)d_out;

  // workspace layout (floats/ints), base assumed 256B-aligned
  float* Wty   = (float*)d_ws;              // 5*4096
  float* hA    = Wty + EDIM * 4096;         // NN*64
  float* hB    = hA + NN * HD;              // NN*64
  float* hC    = hB + NN * HD;              // NN*64
  float* W_ihT = hC + NN * HD;              // 128*256
  float* W_hhT = W_ihT + 2 * HD * 4 * HD;   // 64*256
  int2*  sd    = (int2*)(W_hhT + HD * 4 * HD); // NE int2

  k_main<<<512, 256, 0, stream>>>(node_feat, node_type, edge_type, edge_index,
                                  W_emb, b_emb, W_e1, b_e1, W_e2, b_e2,
                                  W_ih, W_hh, Wty, hA, hB, W_ihT, W_hhT, sd);

  // it 0: hA -> hB (zero hC) | it 1: hB -> hC (zero hA) | it 2: hC -> hA
  k_mp<<<2560, 256, 0, stream>>>(sd, Wty, hA, hB, hC,
                                 roots + 0 * HD * HD, conv_bias + 0 * HD);
  k_mp<<<2560, 256, 0, stream>>>(sd, Wty, hB, hC, hA,
                                 roots + 1 * HD * HD, conv_bias + 1 * HD);
  k_mp<<<2560, 256, 0, stream>>>(sd, Wty, hC, hA, (float*)0,
                                 roots + 2 * HD * HD, conv_bias + 2 * HD);

  k_s2s<<<NB, 256, 0, stream>>>(hA, batch, W_ihT, W_hhT, b_ih, b_hh,
                                W_o1, b_o1, W_o2, b_o2, out);
}

// Round 16
// 202.247 us; speedup vs baseline: 1.6553x; 1.6553x over previous
//
#include <hip/hip_runtime.h>
#include <math.h>

// ---------------------------------------------------------------------------
// MPNNPropPred: N=20000 nodes, E=50000 edges, B=128 graphs, H=64,
// FEAT=28, N_TYPES=100, EDGE_DIM=5, MP_ITER=3, S2S_IT=4. All f32.
// R20 == R18 reverted (205.2 us, session-best verified). R19's boundary
//   elision (self-prefix place) re-created a serial dependent load chain
//   (196-iter scan per block, 145-166 us) — third instance of the session's
//   recurring lesson: serial dependent chains cost ~0.5-1 us/iter on this
//   machine. Final structure:
//     k_pre  : CSR starts + per-block edge-type counts (atomic-free)
//     k_main : edgemats (latency-robust 64-blk) | place (bc-prefix) |
//              LSTM transposes | embed (VGPR-hoisted) | zero hB
//     k_mp x3: fused root(atomicAdd into zeroed tgt) + zero-next +
//              edge messages (staged vector loads + readlane, EPW=7)
//     k_s2s  : Set2Set + output MLP (padded LDS, transposed LSTM weights)
//   6 dispatches. Floor analysis: ~145 us bodies (3x ~35 us fabric-latency
//   -bound msg phases, invariant across 7 tested variants) + ~60 us
//   boundaries; persistent-kernel alternatives regressed or crashed.
// ---------------------------------------------------------------------------

#define NN 20000
#define NE 50000
#define NB 128
#define HD 64
#define NFEAT 28
#define NTYPES 100
#define EDIM 5
#define MPIT 3
#define S2SIT 4
#define NBLK_E ((NE + 255) / 256)  // 196 fixed-range edge blocks
#define SMAX 224                   // nodes cached in LDS (max graph ~195)
#define HP (HD + 1)                // padded LDS row stride
#define EPW 7                      // edges per wave in k_mp (8192 waves)

__device__ __forceinline__ float sigm(float x) {
  return 1.0f / (1.0f + expf(-x));
}

__device__ __forceinline__ float rdlane(float v, int l) {
  return __uint_as_float(__builtin_amdgcn_readlane(__float_as_uint(v), l));
}

// --- k_pre: CSR starts + per-block edge-type counts (all independent) ---
__global__ __launch_bounds__(256) void k_pre(
    const int* __restrict__ batch, const int* __restrict__ etype,
    int* __restrict__ gstart, int* __restrict__ bc) {
  __shared__ int wcc[4][EDIM];
  const int tid = threadIdx.x;
  const int lane = tid & 63;
  const int wv = tid >> 6;
  const int blk = blockIdx.x;
  const int gtid = (blk << 8) + tid;
  const int nthr = gridDim.x << 8;

  // per-block edge-type counts (blocks 0..195), atomic-free
  if (blk < NBLK_E) {
    int e = (blk << 8) + tid;
    int ty = (e < NE) ? etype[e] : -1;
    #pragma unroll
    for (int t = 0; t < EDIM; ++t) {
      unsigned long long m = __ballot(ty == t);
      if (lane == 0) wcc[wv][t] = __popcll(m);
    }
    __syncthreads();
    if (tid < EDIM)
      bc[blk * EDIM + tid] = wcc[0][tid] + wcc[1][tid] + wcc[2][tid] + wcc[3][tid];
  }

  // CSR starts for sorted batch vector
  for (int n = gtid; n < NN; n += nthr) {
    int b = batch[n];
    if (n == 0)
      for (int t = 0; t <= b; ++t) gstart[t] = 0;
    int bn = (n + 1 < NN) ? batch[n + 1] : NB;
    for (int t = b + 1; t <= bn; ++t) gstart[t] = n + 1;
  }
}

// --- k_main: edgemats | place | LSTM transposes | embed | zero hB ---
__global__ __launch_bounds__(256) void k_main(
    const float* __restrict__ feat, const int* __restrict__ ntype,
    const int* __restrict__ etype, const int* __restrict__ ei,
    const float* __restrict__ W_emb, const float* __restrict__ b_emb,
    const float* __restrict__ W_e1, const float* __restrict__ b_e1,
    const float* __restrict__ W_e2, const float* __restrict__ b_e2,
    const float* __restrict__ W_ih, const float* __restrict__ W_hh,
    const int* __restrict__ bc,
    float* __restrict__ Wty, float* __restrict__ hA, float* __restrict__ hB,
    float* __restrict__ W_ihT, float* __restrict__ W_hhT,
    int2* __restrict__ sd) {
  __shared__ float sv[EDIM][HD];       // relu(W_e1+b_e1) per type
  __shared__ float red[4][EDIM][HD];   // j-group partial sums
  __shared__ int s_base[EDIM];
  __shared__ int wc[4][EDIM];
  const int tid = threadIdx.x;
  const int lane = tid & 63;
  const int wv = tid >> 6;
  const int blk = blockIdx.x;
  const int nblk = gridDim.x;
  const int nthr = nblk << 8;
  const int gtid = (blk << 8) + tid;
  const int gw = (blk << 2) + wv;
  const int nwave = nblk << 2;

  // 1) edge-type weight matrices, latency-robust (blocks 0..63):
  //    thread (jg,l): 16 coalesced W_e2 loads, 5 type-accs, LDS reduce.
  if (blk < 64) {
    int mbase = blk * 64;
    for (int idx = tid; idx < EDIM * HD; idx += 256) {
      int t = idx >> 6, j = idx & 63;
      float x = W_e1[t * HD + j] + b_e1[j];
      sv[t][j] = x > 0.f ? x : 0.f;
    }
    __syncthreads();
    int l = tid & 63, jg = tid >> 6;
    float acc[EDIM] = {0.f, 0.f, 0.f, 0.f, 0.f};
    #pragma unroll
    for (int jj = 0; jj < 16; ++jj) {
      int j = jg * 16 + jj;
      float w2 = W_e2[j * 4096 + mbase + l];   // coalesced, independent
      #pragma unroll
      for (int t = 0; t < EDIM; ++t) acc[t] = fmaf(sv[t][j], w2, acc[t]);
    }
    #pragma unroll
    for (int t = 0; t < EDIM; ++t) red[jg][t][l] = acc[t];
    __syncthreads();
    for (int idx = tid; idx < EDIM * HD; idx += 256) {
      int t = idx >> 6, m = idx & 63;
      float s = red[0][t][m] + red[1][t][m] + red[2][t][m] + red[3][t][m];
      Wty[t * 4096 + mbase + m] = s + b_e2[mbase + m];
    }
  }

  // 2) place edges grouped by type (blocks 64..259; bc from k_pre)
  if (blk >= 64 && blk < 64 + NBLK_E) {
    int pblk = blk - 64;
    if (wv == 0) {
      int part[EDIM], tot[EDIM];
      #pragma unroll
      for (int t = 0; t < EDIM; ++t) { part[t] = 0; tot[t] = 0; }
      for (int b = lane; b < NBLK_E; b += 64) {
        #pragma unroll
        for (int t = 0; t < EDIM; ++t) {
          int x = bc[b * EDIM + t];
          tot[t] += x;
          if (b < pblk) part[t] += x;
        }
      }
      #pragma unroll
      for (int t = 0; t < EDIM; ++t) {
        #pragma unroll
        for (int off = 32; off; off >>= 1) {
          tot[t]  += __shfl_xor(tot[t],  off, 64);
          part[t] += __shfl_xor(part[t], off, 64);
        }
      }
      if (lane == 0) {
        int run = 0;
        #pragma unroll
        for (int t = 0; t < EDIM; ++t) {
          s_base[t] = run + part[t];
          run += tot[t];
        }
      }
    }
    int e = (pblk << 8) + tid;
    int ty = (e < NE) ? etype[e] : -1;
    int svv = 0, dv = 0;
    if (e < NE) { svv = ei[e]; dv = ei[NE + e]; }
    int rank = 0;
    #pragma unroll
    for (int t = 0; t < EDIM; ++t) {
      unsigned long long m = __ballot(ty == t);
      if (lane == 0) wc[wv][t] = __popcll(m);
      if (ty == t) rank = __popcll(m & ((1ull << lane) - 1ull));
    }
    __syncthreads();
    if (ty >= 0) {
      int base = s_base[ty];
      for (int w = 0; w < wv; ++w) base += wc[w][ty];
      sd[base + rank] = make_int2(svv | (ty << 16), dv);
    }
  }

  // 3) LSTM weight transposes (coalesced writes)
  for (int o = gtid; o < 2 * HD * 4 * HD; o += nthr)       // W_ihT [128][256]
    W_ihT[o] = W_ih[(o & 255) * 128 + (o >> 8)];
  for (int o = gtid; o < HD * 4 * HD; o += nthr)           // W_hhT [64][256]
    W_hhT[o] = W_hh[(o & 255) * 64 + (o >> 8)];

  // 4) node embedding: wave per node, feature weights hoisted to VGPRs
  {
    float wf[NFEAT];
    #pragma unroll
    for (int f = 0; f < NFEAT; ++f) wf[f] = W_emb[(NTYPES + f) * HD + lane];
    float bb = b_emb[lane];
    for (int n = gw; n < NN; n += nwave) {
      int nu = __builtin_amdgcn_readfirstlane(n);
      int t = __builtin_amdgcn_readfirstlane(ntype[nu]);
      const float* row = feat + nu * NFEAT;        // wave-uniform -> s_load
      float acc = bb + W_emb[t * HD + lane];
      #pragma unroll
      for (int f = 0; f < NFEAT; ++f) acc = fmaf(row[f], wf[f], acc);
      hA[nu * HD + lane] = acc;
    }
  }

  // 5) zero hB (target of first MP iteration)
  {
    float4 z = make_float4(0.f, 0.f, 0.f, 0.f);
    for (int i = gtid; i < NN * HD / 4; i += nthr)
      reinterpret_cast<float4*>(hB)[i] = z;
  }
}

// --- one MP iteration (R12-proven, verbatim): blocks 0..511 root
//     (atomicAdd into zeroed tgt) + zero next target; blocks 512..2559
//     edge messages with staged vector loads + readlane broadcast.
__global__ __launch_bounds__(256) void k_mp(
    const int2* __restrict__ sd,
    const float* __restrict__ Wty, const float* __restrict__ hsrc,
    float* __restrict__ htgt, float* __restrict__ hzero,
    const float* __restrict__ root, const float* __restrict__ bias) {
  const int lane = threadIdx.x & 63;
  const int wv = threadIdx.x >> 6;
  const int blk = blockIdx.x;

  if (blk < 512) {
    // NNConv root matvec + bias, atomicAdd into zero-initialized target
    float w[HD];
    #pragma unroll
    for (int k = 0; k < HD; ++k) w[k] = root[k * HD + lane];
    float bb = bias[lane];
    int rw = (blk << 2) + wv;                    // 0..2047
    for (int n = rw; n < NN; n += 2048) {
      int nu = __builtin_amdgcn_readfirstlane(n);
      const float* row = hsrc + nu * HD;         // wave-uniform -> s_load
      float a0 = bb, a1 = 0.f, a2 = 0.f, a3 = 0.f;
      #pragma unroll
      for (int k = 0; k < HD; k += 4) {
        a0 = fmaf(row[k + 0], w[k + 0], a0);
        a1 = fmaf(row[k + 1], w[k + 1], a1);
        a2 = fmaf(row[k + 2], w[k + 2], a2);
        a3 = fmaf(row[k + 3], w[k + 3], a3);
      }
      atomicAdd(&htgt[nu * HD + lane], (a0 + a1) + (a2 + a3));
    }
    // zero next iteration's target (overlaps with this phase's traffic)
    if (hzero) {
      float4 z = make_float4(0.f, 0.f, 0.f, 0.f);
      for (int i = (blk << 8) + threadIdx.x; i < NN * HD / 4; i += 512 * 256)
        reinterpret_cast<float4*>(hzero)[i] = z;
    }
  } else {
    // edge messages: wave handles EPW consecutive type-sorted edges
    int wid = ((blk - 512) << 2) + wv;           // 0..8191
    int beg = wid * EPW;
    if (beg >= NE) return;
    int len = NE - beg; if (len > EPW) len = EPW;

    // one per-lane load fetches the wave's edge records (lanes 0..len-1)
    int2 ed = sd[beg + (lane < len ? lane : len - 1)];

    // stage all h rows as independent coalesced vector loads (in flight)
    float hv[EPW];
    #pragma unroll
    for (int j = 0; j < EPW; ++j) {
      int sx = __builtin_amdgcn_readlane(ed.x, j < EPW ? j : 0);
      // j >= len reads lane len-1's record: valid address, result unused
      hv[j] = hsrc[(sx & 0xFFFF) * HD + lane];
    }

    int curt = -1;
    float w[HD];
    #pragma unroll
    for (int j = 0; j < EPW; ++j) {
      if (j >= len) break;
      int ex = __builtin_amdgcn_readlane(ed.x, j);
      int dj = __builtin_amdgcn_readlane(ed.y, j);
      int ty = ex >> 16;
      if (ty != curt) {                          // rare: type-segment switch
        curt = ty;
        #pragma unroll
        for (int k = 0; k < HD; ++k) w[k] = Wty[ty * 4096 + k * HD + lane];
      }
      float a0 = 0.f, a1 = 0.f, a2 = 0.f, a3 = 0.f;
      #pragma unroll
      for (int k = 0; k < HD; k += 4) {
        a0 = fmaf(rdlane(hv[j], k + 0), w[k + 0], a0);
        a1 = fmaf(rdlane(hv[j], k + 1), w[k + 1], a1);
        a2 = fmaf(rdlane(hv[j], k + 2), w[k + 2], a2);
        a3 = fmaf(rdlane(hv[j], k + 3), w[k + 3], a3);
      }
      atomicAdd(&htgt[dj * HD + lane], (a0 + a1) + (a2 + a3));
    }
  }
}

// --- Set2Set + output MLP, one block per graph (proven R4 body) ---
__global__ __launch_bounds__(256) void k_s2s(
    const float* __restrict__ h, const int* __restrict__ gstart,
    const float* __restrict__ W_ihT, const float* __restrict__ W_hhT,
    const float* __restrict__ b_ih, const float* __restrict__ b_hh,
    const float* __restrict__ W_o1, const float* __restrict__ b_o1,
    const float* __restrict__ W_o2, const float* __restrict__ b_o2,
    float* __restrict__ out) {
  __shared__ float hs[SMAX * HP];     // 58240 B, padded rows
  __shared__ float ebuf[SMAX];
  __shared__ float qstar[2 * HD];
  __shared__ float hxs[HD], cxs[HD], gates[4 * HD];
  __shared__ float redM[4], redS[4], redR[4][HD];
  __shared__ float hid[HD];
  int b = blockIdx.x;
  int tid = threadIdx.x;
  int lane = tid & 63, wv = tid >> 6;

  int st = gstart[b], en = gstart[b + 1];
  int cnt = en - st;
  int cached = cnt < SMAX ? cnt : SMAX;

  // stage node block into padded LDS (coalesced float4 global reads)
  int total = cached * HD;
  for (int base = tid * 4; base < total; base += 1024) {
    float4 v = *reinterpret_cast<const float4*>(h + st * HD + base);
    int n = base >> 6, k = base & 63;
    float* row = hs + n * HP + k;
    row[0] = v.x; row[1] = v.y; row[2] = v.z; row[3] = v.w;
  }
  if (tid < 2 * HD) qstar[tid] = 0.f;
  if (tid < HD) { hxs[tid] = 0.f; cxs[tid] = 0.f; }
  __syncthreads();

  for (int it = 0; it < S2SIT; ++it) {
    // LSTM gates via transposed weights (coalesced): tid = gate index
    float acc0 = b_ih[tid] + b_hh[tid], acc1 = 0.f;
    #pragma unroll 8
    for (int j = 0; j < 2 * HD; j += 2) {
      acc0 = fmaf(qstar[j],     W_ihT[j * 256 + tid],       acc0);
      acc1 = fmaf(qstar[j + 1], W_ihT[(j + 1) * 256 + tid], acc1);
    }
    #pragma unroll 8
    for (int j = 0; j < HD; j += 2) {
      acc0 = fmaf(hxs[j],     W_hhT[j * 256 + tid],       acc0);
      acc1 = fmaf(hxs[j + 1], W_hhT[(j + 1) * 256 + tid], acc1);
    }
    gates[tid] = acc0 + acc1;
    __syncthreads();
    if (tid < HD) {
      float ig = sigm(gates[tid]);
      float fg = sigm(gates[HD + tid]);
      float gg = tanhf(gates[2 * HD + tid]);
      float og = sigm(gates[3 * HD + tid]);
      float c = fmaf(fg, cxs[tid], ig * gg);
      cxs[tid] = c;
      hxs[tid] = og * tanhf(c);
    }
    __syncthreads();

    // pass 1: per-thread dot (thread = node), padded LDS rows
    float e = -1e30f;
    if (tid < cached) {
      const float* row = hs + tid * HP;
      float d0 = 0.f, d1 = 0.f;
      #pragma unroll 8
      for (int k = 0; k < HD; k += 2) {
        d0 = fmaf(row[k],     hxs[k],     d0);
        d1 = fmaf(row[k + 1], hxs[k + 1], d1);
      }
      e = d0 + d1;
      ebuf[tid] = e;
    }
    float m = e;
    #pragma unroll
    for (int off = 32; off; off >>= 1) m = fmaxf(m, __shfl_xor(m, off, 64));
    float qreg = hxs[lane];
    for (int n = cached + wv; n < cnt; n += 4) {   // overflow tail
      float ev = h[(st + n) * HD + lane] * qreg;
      #pragma unroll
      for (int off = 32; off; off >>= 1) ev += __shfl_xor(ev, off, 64);
      m = fmaxf(m, ev);
    }
    if (lane == 0) redM[wv] = m;
    __syncthreads();
    float M = fmaxf(fmaxf(redM[0], redM[1]), fmaxf(redM[2], redM[3]));

    // pass 2a: a = exp(e-M), per-wave partial sum
    float sp = 0.f;
    if (tid < cached) {
      float a = expf(ebuf[tid] - M);
      ebuf[tid] = a;
      sp = a;
    }
    #pragma unroll
    for (int off = 32; off; off >>= 1) sp += __shfl_xor(sp, off, 64);
    __syncthreads();   // ebuf(a) visible to all waves

    // pass 2b: r = sum_n a[n] * h_n  (lane = feature)
    float r = 0.f;
    for (int n = wv; n < cached; n += 4)
      r = fmaf(ebuf[n], hs[n * HP + lane], r);
    float s_tail = 0.f;
    for (int n = cached + wv; n < cnt; n += 4) {   // overflow tail
      float v = h[(st + n) * HD + lane];
      float ev = v * qreg;
      #pragma unroll
      for (int off = 32; off; off >>= 1) ev += __shfl_xor(ev, off, 64);
      float a = expf(ev - M);
      s_tail += a;
      r = fmaf(a, v, r);
    }
    if (lane == 0) redS[wv] = sp + s_tail;
    redR[wv][lane] = r;
    __syncthreads();
    if (tid < HD) {
      float S = redS[0] + redS[1] + redS[2] + redS[3];
      float R = redR[0][tid] + redR[1][tid] + redR[2][tid] + redR[3][tid];
      if (S == 0.f) S = 1.f;            // empty-graph guard (matches ref)
      qstar[tid] = hxs[tid];
      qstar[HD + tid] = R / S;
    }
    __syncthreads();
  }

  // output MLP: relu(qstar @ W_o1 + b_o1) @ W_o2 + b_o2
  if (tid < HD) {
    float acc = b_o1[tid];
    #pragma unroll 8
    for (int i = 0; i < 2 * HD; ++i)
      acc = fmaf(qstar[i], W_o1[i * HD + tid], acc);
    hid[tid] = acc > 0.f ? acc : 0.f;
  }
  __syncthreads();
  if (tid < HD) {
    float p = hid[tid] * W_o2[tid];
    #pragma unroll
    for (int off = 32; off; off >>= 1) p += __shfl_xor(p, off, 64);
    if (tid == 0) out[b] = p + b_o2[0];
  }
}

extern "C" void kernel_launch(void* const* d_in, const int* in_sizes, int n_in,
                              void* d_out, int out_size, void* d_ws, size_t ws_size,
                              hipStream_t stream) {
  const float* node_feat = (const float*)d_in[0];
  const int*   node_type = (const int*)d_in[1];
  const int*   edge_index= (const int*)d_in[2];
  const int*   edge_type = (const int*)d_in[3];
  const int*   batch     = (const int*)d_in[4];
  const float* W_emb     = (const float*)d_in[5];
  const float* b_emb     = (const float*)d_in[6];
  const float* W_e1      = (const float*)d_in[7];
  const float* b_e1      = (const float*)d_in[8];
  const float* W_e2      = (const float*)d_in[9];
  const float* b_e2      = (const float*)d_in[10];
  const float* roots     = (const float*)d_in[11];
  const float* conv_bias = (const float*)d_in[12];
  const float* W_ih      = (const float*)d_in[13];
  const float* W_hh      = (const float*)d_in[14];
  const float* b_ih      = (const float*)d_in[15];
  const float* b_hh      = (const float*)d_in[16];
  const float* W_o1      = (const float*)d_in[17];
  const float* b_o1      = (const float*)d_in[18];
  const float* W_o2      = (const float*)d_in[19];
  const float* b_o2      = (const float*)d_in[20];
  float* out = (float*)d_out;

  // workspace layout (floats/ints), base assumed 256B-aligned
  float* Wty   = (float*)d_ws;              // 5*4096
  float* hA    = Wty + EDIM * 4096;         // NN*64
  float* hB    = hA + NN * HD;              // NN*64
  float* hC    = hB + NN * HD;              // NN*64
  float* W_ihT = hC + NN * HD;              // 128*256
  float* W_hhT = W_ihT + 2 * HD * 4 * HD;   // 64*256
  int2*  sd    = (int2*)(W_hhT + HD * 4 * HD); // NE int2
  int*   gstart= (int*)(sd + NE);           // NB+1 (pad to 136)
  int*   bc    = gstart + 136;              // NBLK_E*EDIM

  k_pre<<<256, 256, 0, stream>>>(batch, edge_type, gstart, bc);
  k_main<<<512, 256, 0, stream>>>(node_feat, node_type, edge_type, edge_index,
                                  W_emb, b_emb, W_e1, b_e1, W_e2, b_e2,
                                  W_ih, W_hh, bc, Wty, hA, hB, W_ihT, W_hhT, sd);

  // it 0: hA -> hB (zero hC) | it 1: hB -> hC (zero hA) | it 2: hC -> hA
  k_mp<<<2560, 256, 0, stream>>>(sd, Wty, hA, hB, hC,
                                 roots + 0 * HD * HD, conv_bias + 0 * HD);
  k_mp<<<2560, 256, 0, stream>>>(sd, Wty, hB, hC, hA,
                                 roots + 1 * HD * HD, conv_bias + 1 * HD);
  k_mp<<<2560, 256, 0, stream>>>(sd, Wty, hC, hA, (float*)0,
                                 roots + 2 * HD * HD, conv_bias + 2 * HD);

  k_s2s<<<NB, 256, 0, stream>>>(hA, gstart, W_ihT, W_hhT, b_ih, b_hh,
                                W_o1, b_o1, W_o2, b_o2, out);
}